// Round 12
// baseline (136.719 us; speedup 1.0000x reference)
//
#include <hip/hip_runtime.h>

// NPairDiscriminator: N=8192, D=128, tau=0.5. f32 inputs, f32 scalar output.
// loss = mean_i 0.5*(log d1_i + log d2_i - 4*(n1_i . n2_i))
//   d1_i = T[i] - exp(|n1_i|^2/tau),  d2_i = T[NR+i] - exp(|n2_i|^2/tau)
// T[q] = sum over ALL 16384 keys of exp((n_q . n_j)/tau), MFMA+exp2 fused.

#define NR 8192
#define DIM 128
#define SCALE_EXP2 2.885390081777927f   // 1/(tau*ln2)
#define LOG2E 1.442695040888963f
#define LN2 0.6931471805599453f
#define NT 16                            // 64-key tiles per 1024-key slice

typedef __attribute__((ext_vector_type(8))) short short8;    // 8 bf16 (MFMA A/B frag)
typedef __attribute__((ext_vector_type(4))) float f32x4;
typedef __attribute__((ext_vector_type(16))) float f32x16;   // 32x32 MFMA C/D frag

__device__ unsigned short gN[2 * NR * DIM];   // [n1; n2] normalized bf16 (keys)
__device__ unsigned short gNs[2 * NR * DIM];  // gN * SCALE_EXP2 bf16 (queries)
__device__ float gT[2 * NR];                  // row sums
__device__ float gACC;

__device__ inline float b2f(unsigned short h) {
    union { unsigned int u; float f; } x; x.u = ((unsigned int)h) << 16; return x.f;
}
__device__ inline unsigned short f2b(float f) {   // RNE f32->bf16
    union { float f; unsigned int u; } x; x.f = f;
    return (unsigned short)((x.u + 0x7FFFu + ((x.u >> 16) & 1u)) >> 16);
}
__device__ inline short8 ldf8(const float* __restrict__ p) {   // 8 f32 -> bf16 frag
    f32x4 a = *(const f32x4*)p;
    f32x4 b = *(const f32x4*)(p + 4);
    short8 r;
#pragma unroll
    for (int j = 0; j < 4; ++j) r[j] = (short)f2b(a[j]);
#pragma unroll
    for (int j = 0; j < 4; ++j) r[4 + j] = (short)f2b(b[j]);
    return r;
}
__device__ inline f32x16 zero16() {
    f32x16 z;
#pragma unroll
    for (int i = 0; i < 16; ++i) z[i] = 0.0f;
    return z;
}
__device__ inline void gload_lds16(const void* g, void* l) {   // 16B async global->LDS
    __builtin_amdgcn_global_load_lds(
        (const __attribute__((address_space(1))) unsigned int*)g,
        (__attribute__((address_space(3))) unsigned int*)l, 16, 0, 0);
}

// ---------- fused projection: n = normalize(fc2(elu(fc1(z)))); zeroes gT, d_out ----------
// grid (64, 2), block 256 = 4 waves x 32 rows.
__global__ __launch_bounds__(256) void k_proj(
        const float* __restrict__ Z1, const float* __restrict__ Z2,
        const float* __restrict__ W1, const float* __restrict__ B1,
        const float* __restrict__ W2, const float* __restrict__ B2,
        float* __restrict__ out) {
    __shared__ unsigned short hfrag[4][8][64][8];   // [wave][kc][lane][j], 32 KB
    int t = threadIdx.x, w = t >> 6, l = t & 63;
    int lr = l & 31, lh = l >> 5;
    const float* Z = blockIdx.y ? Z2 : Z1;
    long rbase = (long)blockIdx.x * 128 + w * 32;

    int gi = ((int)blockIdx.y * 64 + (int)blockIdx.x) * 256 + t;
    if (gi < 2 * NR) gT[gi] = 0.0f;
    if (gi == 0) { gACC = 0.0f; out[0] = 0.0f; }

    short8 zf[8];
#pragma unroll
    for (int kc = 0; kc < 8; ++kc)
        zf[kc] = ldf8(Z + (rbase + lr) * DIM + kc * 16 + lh * 8);

    // layer 1 + elu, scatter to LDS in A-fragment layout
#pragma unroll
    for (int tt = 0; tt < 4; ++tt) {
        short8 wf[8];
#pragma unroll
        for (int kc = 0; kc < 8; ++kc)
            wf[kc] = ldf8(W1 + (tt * 32 + lr) * DIM + kc * 16 + lh * 8);
        f32x16 a = zero16();
#pragma unroll
        for (int kc = 0; kc < 8; ++kc)
            a = __builtin_amdgcn_mfma_f32_32x32x16_bf16(zf[kc], wf[kc], a, 0, 0, 0);
        float bias = B1[tt * 32 + lr];
        int col = tt * 32 + lr;
#pragma unroll
        for (int r = 0; r < 16; ++r) {
            float v = a[r] + bias;
            if (v <= 0.0f) v = __builtin_amdgcn_exp2f(v * LOG2E) - 1.0f;   // elu
            int ro = (r & 3) + 8 * (r >> 2) + 4 * lh;
            hfrag[w][col >> 4][ro | (((col >> 3) & 1) << 5)][col & 7] = f2b(v);
        }
    }
    __syncthreads();

    short8 af[8];
#pragma unroll
    for (int kc = 0; kc < 8; ++kc)
        af[kc] = *(const short8*)&hfrag[w][kc][l][0];

    f32x16 acc[4];
#pragma unroll
    for (int tt = 0; tt < 4; ++tt) {
        short8 wf[8];
#pragma unroll
        for (int kc = 0; kc < 8; ++kc)
            wf[kc] = ldf8(W2 + (tt * 32 + lr) * DIM + kc * 16 + lh * 8);
        f32x16 a = zero16();
#pragma unroll
        for (int kc = 0; kc < 8; ++kc)
            a = __builtin_amdgcn_mfma_f32_32x32x16_bf16(af[kc], wf[kc], a, 0, 0, 0);
        float bias = B2[tt * 32 + lr];
#pragma unroll
        for (int r = 0; r < 16; ++r) a[r] += bias;
        acc[tt] = a;
    }
    float ss[16];
#pragma unroll
    for (int r = 0; r < 16; ++r)
        ss[r] = acc[0][r] * acc[0][r] + acc[1][r] * acc[1][r]
              + acc[2][r] * acc[2][r] + acc[3][r] * acc[3][r];
#pragma unroll
    for (int r = 0; r < 16; ++r) {
        ss[r] += __shfl_xor(ss[r], 1);  ss[r] += __shfl_xor(ss[r], 2);
        ss[r] += __shfl_xor(ss[r], 4);  ss[r] += __shfl_xor(ss[r], 8);
        ss[r] += __shfl_xor(ss[r], 16);
    }
    long nbase = (long)blockIdx.y * NR + rbase;
#pragma unroll
    for (int r = 0; r < 16; ++r) {
        float inv = 1.0f / fmaxf(sqrtf(ss[r]), 1e-12f);
        long row = nbase + (r & 3) + 8 * (r >> 2) + 4 * lh;
#pragma unroll
        for (int tt = 0; tt < 4; ++tt) {
            float v = acc[tt][r] * inv;
            gN[row * DIM + tt * 32 + lr]  = f2b(v);
            gNs[row * DIM + tt * 32 + lr] = f2b(v * SCALE_EXP2);
        }
    }
}

// ---------- fused exp-sim row sums: gT[q] += sum_j exp2(a_q . b_j) ----------
// 64 q-rows/wave: each LDS tile read feeds TWO MFMA chains (LDS wall 40->20 us).
// 512 blocks = 32 q-panels x 16 slices (2 per XCD, L2-resident keys); 2 blocks/CU
// at VGPR ~108 -> 4 waves/SIMD. NO setprio: the builtin is side-effecting and
// blocks the compiler from interleaving the exp chain with the 2nd MFMA chain
// (round-10 regression). launch_bounds min-waves must stay 2 (round-9 spill).
__global__ __launch_bounds__(512, 2) void k_sim() {
    __shared__ char smem[2 * 16384];                 // 2 x (64 keys x 256 B)
    int bid = blockIdx.x;
    int slice = ((bid & 7) << 1) | ((bid >> 3) & 1);   // same-XCD pairs
    int qp = bid >> 4;
    int t = threadIdx.x, w = t >> 6, l = t & 63;
    int lr = l & 31, lh = l >> 5;
    long qbase = (long)qp * 512 + w * 64;
    long kb = (long)slice * 1024;

    short8 qf[2][8];
#pragma unroll
    for (int s = 0; s < 2; ++s)
#pragma unroll
        for (int kc = 0; kc < 8; ++kc)
            qf[s][kc] = *(const short8*)(gNs + (qbase + s * 32 + lr) * DIM + kc * 16 + lh * 8);
    float rs0[16], rs1[16];
#pragma unroll
    for (int r = 0; r < 16; ++r) { rs0[r] = 0.0f; rs1[r] = 0.0f; }

    // stage 64x128 bf16 tile (16 KB): linear LDS dest, inverse-swizzled global src
    // j = (i&~15) | ((i&15) ^ ((i>>4)&7)); read applies the same involution.
#define STAGE(BUF, TILE) do {                                                        \
    const unsigned short* _tb = gN + (kb + (long)(TILE) * 64) * DIM;                 \
    int _j0 = (t & ~15) | ((t & 15) ^ ((t >> 4) & 7));                               \
    gload_lds16(_tb + _j0 * 8, smem + (BUF) * 16384 + w * 1024);                     \
    int _i1 = 512 + t;                                                               \
    int _j1 = (_i1 & ~15) | ((_i1 & 15) ^ ((_i1 >> 4) & 7));                         \
    gload_lds16(_tb + _j1 * 8, smem + (BUF) * 16384 + 8192 + w * 1024);              \
} while (0)

    STAGE(0, 0);
    for (int tt = 0; tt < NT; ++tt) {
        int cur = tt & 1;
        if (tt + 1 < NT) {
            STAGE(cur ^ 1, tt + 1);
            asm volatile("s_waitcnt vmcnt(2)" ::: "memory");   // tile tt arrived
        } else {
            asm volatile("s_waitcnt vmcnt(0)" ::: "memory");
        }
        __builtin_amdgcn_s_barrier();
        const char* bufp = smem + cur * 16384;
#pragma unroll
        for (int ks = 0; ks < 2; ++ks) {
            short8 bf[8];
#pragma unroll
            for (int kc = 0; kc < 8; ++kc) {
                int chunk = ((kc << 1) | lh) ^ (lr & 7);
                bf[kc] = *(const short8*)(bufp + (ks * 32 + lr) * 256 + chunk * 16);
            }
            f32x16 c0 = zero16(), c1 = zero16();
#pragma unroll
            for (int kc = 0; kc < 8; ++kc) {
                c0 = __builtin_amdgcn_mfma_f32_32x32x16_bf16(qf[0][kc], bf[kc], c0, 0, 0, 0);
                c1 = __builtin_amdgcn_mfma_f32_32x32x16_bf16(qf[1][kc], bf[kc], c1, 0, 0, 0);
            }
#pragma unroll
            for (int r = 0; r < 16; ++r) {
                rs0[r] += __builtin_amdgcn_exp2f(c0[r]);
                rs1[r] += __builtin_amdgcn_exp2f(c1[r]);
            }
        }
        __builtin_amdgcn_s_barrier();   // all waves done reading before overwrite
    }
#undef STAGE

#pragma unroll
    for (int r = 0; r < 16; ++r) {
        rs0[r] += __shfl_xor(rs0[r], 1);  rs0[r] += __shfl_xor(rs0[r], 2);
        rs0[r] += __shfl_xor(rs0[r], 4);  rs0[r] += __shfl_xor(rs0[r], 8);
        rs0[r] += __shfl_xor(rs0[r], 16);
        rs1[r] += __shfl_xor(rs1[r], 1);  rs1[r] += __shfl_xor(rs1[r], 2);
        rs1[r] += __shfl_xor(rs1[r], 4);  rs1[r] += __shfl_xor(rs1[r], 8);
        rs1[r] += __shfl_xor(rs1[r], 16);
    }
    if (lr == 0) {   // lanes 0 / 32 own 16 rows each per subtile
#pragma unroll
        for (int r = 0; r < 16; ++r) {
            int ro = (r & 3) + 8 * (r >> 2) + 4 * lh;
            atomicAdd(&gT[qbase + ro], rs0[r]);
            atomicAdd(&gT[qbase + 32 + ro], rs1[r]);
        }
    }
}

// ---------- per-row loss + global mean (writes d_out directly) ----------
__global__ __launch_bounds__(256) void k_loss(float* __restrict__ out) {
    int t = threadIdx.x, w = t >> 6, l = t & 63;
    int gw = blockIdx.x * 4 + w;   // 512 waves
    float lsum = 0.0f;
    for (int row = gw; row < NR; row += 512) {
        unsigned int pa = *(const unsigned int*)(gN + (long)row * DIM + l * 2);
        unsigned int pb = *(const unsigned int*)(gN + (long)(NR + row) * DIM + l * 2);
        float a0 = b2f((unsigned short)(pa & 0xFFFFu)), a1 = b2f((unsigned short)(pa >> 16));
        float b0 = b2f((unsigned short)(pb & 0xFFFFu)), b1 = b2f((unsigned short)(pb >> 16));
        float sd1 = a0 * a0 + a1 * a1;
        float sd2 = b0 * b0 + b1 * b1;
        float cr  = a0 * b0 + a1 * b1;
#pragma unroll
        for (int off = 1; off < 64; off <<= 1) {
            sd1 += __shfl_xor(sd1, off);
            sd2 += __shfl_xor(sd2, off);
            cr  += __shfl_xor(cr,  off);
        }
        float d1 = gT[row]      - __builtin_amdgcn_exp2f(sd1 * SCALE_EXP2);
        float d2 = gT[NR + row] - __builtin_amdgcn_exp2f(sd2 * SCALE_EXP2);
        float v = (__builtin_amdgcn_logf(d1) + __builtin_amdgcn_logf(d2)) * LN2 - 4.0f * cr;
        if (l == 0) lsum += v;
    }
    if (l == 0) atomicAdd(out, lsum * (0.5f / 8192.0f));
}

extern "C" void kernel_launch(void* const* d_in, const int* in_sizes, int n_in,
                              void* d_out, int out_size, void* d_ws, size_t ws_size,
                              hipStream_t stream) {
    const float* z1 = (const float*)d_in[0];
    const float* z2 = (const float*)d_in[1];
    const float* w1 = (const float*)d_in[2];
    const float* b1 = (const float*)d_in[3];
    const float* w2 = (const float*)d_in[4];
    const float* b2 = (const float*)d_in[5];

    k_proj<<<dim3(64, 2), 256, 0, stream>>>(z1, z2, w1, b1, w2, b2, (float*)d_out);
    k_sim<<<dim3(512), 512, 0, stream>>>();
    k_loss<<<dim3(128), 256, 0, stream>>>((float*)d_out);
}

// Round 13
// 135.305 us; speedup vs baseline: 1.0105x; 1.0105x over previous
//
#include <hip/hip_runtime.h>

// NPairDiscriminator: N=8192, D=128, tau=0.5. f32 inputs, f32 scalar output.
// loss = mean_i 0.5*(log d1_i + log d2_i - 4*(n1_i . n2_i))
//   d1_i = T[i] - exp(|n1_i|^2/tau),  d2_i = T[NR+i] - exp(|n2_i|^2/tau)
// T[q] = sum over ALL 16384 keys of exp((n_q . n_j)/tau), MFMA+exp2 fused.

#define NR 8192
#define DIM 128
#define SCALE_EXP2 2.885390081777927f   // 1/(tau*ln2)
#define LOG2E 1.442695040888963f
#define LN2 0.6931471805599453f
#define NT 32                            // 64-key tiles per 2048-key slice

typedef __attribute__((ext_vector_type(8))) short short8;    // 8 bf16 (MFMA A/B frag)
typedef __attribute__((ext_vector_type(4))) float f32x4;
typedef __attribute__((ext_vector_type(16))) float f32x16;   // 32x32 MFMA C/D frag

__device__ unsigned short gN[2 * NR * DIM];   // [n1; n2] normalized bf16 (keys)
__device__ unsigned short gNs[2 * NR * DIM];  // gN * SCALE_EXP2 bf16 (queries)
__device__ float gT[2 * NR];                  // row sums
__device__ float gACC;

__device__ inline float b2f(unsigned short h) {
    union { unsigned int u; float f; } x; x.u = ((unsigned int)h) << 16; return x.f;
}
__device__ inline unsigned short f2b(float f) {   // RNE f32->bf16
    union { float f; unsigned int u; } x; x.f = f;
    return (unsigned short)((x.u + 0x7FFFu + ((x.u >> 16) & 1u)) >> 16);
}
__device__ inline short8 ldf8(const float* __restrict__ p) {   // 8 f32 -> bf16 frag
    f32x4 a = *(const f32x4*)p;
    f32x4 b = *(const f32x4*)(p + 4);
    short8 r;
#pragma unroll
    for (int j = 0; j < 4; ++j) r[j] = (short)f2b(a[j]);
#pragma unroll
    for (int j = 0; j < 4; ++j) r[4 + j] = (short)f2b(b[j]);
    return r;
}
__device__ inline f32x16 zero16() {
    f32x16 z;
#pragma unroll
    for (int i = 0; i < 16; ++i) z[i] = 0.0f;
    return z;
}
__device__ inline void gload_lds16(const void* g, void* l) {   // 16B async global->LDS
    __builtin_amdgcn_global_load_lds(
        (const __attribute__((address_space(1))) unsigned int*)g,
        (__attribute__((address_space(3))) unsigned int*)l, 16, 0, 0);
}

// ---------- fused projection: n = normalize(fc2(elu(fc1(z)))); zeroes gT, d_out ----------
// grid (64, 2), block 256 = 4 waves x 32 rows.
__global__ __launch_bounds__(256) void k_proj(
        const float* __restrict__ Z1, const float* __restrict__ Z2,
        const float* __restrict__ W1, const float* __restrict__ B1,
        const float* __restrict__ W2, const float* __restrict__ B2,
        float* __restrict__ out) {
    __shared__ unsigned short hfrag[4][8][64][8];   // [wave][kc][lane][j], 32 KB
    int t = threadIdx.x, w = t >> 6, l = t & 63;
    int lr = l & 31, lh = l >> 5;
    const float* Z = blockIdx.y ? Z2 : Z1;
    long rbase = (long)blockIdx.x * 128 + w * 32;

    int gi = ((int)blockIdx.y * 64 + (int)blockIdx.x) * 256 + t;
    if (gi < 2 * NR) gT[gi] = 0.0f;
    if (gi == 0) { gACC = 0.0f; out[0] = 0.0f; }

    short8 zf[8];
#pragma unroll
    for (int kc = 0; kc < 8; ++kc)
        zf[kc] = ldf8(Z + (rbase + lr) * DIM + kc * 16 + lh * 8);

    // layer 1 + elu, scatter to LDS in A-fragment layout
#pragma unroll
    for (int tt = 0; tt < 4; ++tt) {
        short8 wf[8];
#pragma unroll
        for (int kc = 0; kc < 8; ++kc)
            wf[kc] = ldf8(W1 + (tt * 32 + lr) * DIM + kc * 16 + lh * 8);
        f32x16 a = zero16();
#pragma unroll
        for (int kc = 0; kc < 8; ++kc)
            a = __builtin_amdgcn_mfma_f32_32x32x16_bf16(zf[kc], wf[kc], a, 0, 0, 0);
        float bias = B1[tt * 32 + lr];
        int col = tt * 32 + lr;
#pragma unroll
        for (int r = 0; r < 16; ++r) {
            float v = a[r] + bias;
            if (v <= 0.0f) v = __builtin_amdgcn_exp2f(v * LOG2E) - 1.0f;   // elu
            int ro = (r & 3) + 8 * (r >> 2) + 4 * lh;
            hfrag[w][col >> 4][ro | (((col >> 3) & 1) << 5)][col & 7] = f2b(v);
        }
    }
    __syncthreads();

    short8 af[8];
#pragma unroll
    for (int kc = 0; kc < 8; ++kc)
        af[kc] = *(const short8*)&hfrag[w][kc][l][0];

    f32x16 acc[4];
#pragma unroll
    for (int tt = 0; tt < 4; ++tt) {
        short8 wf[8];
#pragma unroll
        for (int kc = 0; kc < 8; ++kc)
            wf[kc] = ldf8(W2 + (tt * 32 + lr) * DIM + kc * 16 + lh * 8);
        f32x16 a = zero16();
#pragma unroll
        for (int kc = 0; kc < 8; ++kc)
            a = __builtin_amdgcn_mfma_f32_32x32x16_bf16(af[kc], wf[kc], a, 0, 0, 0);
        float bias = B2[tt * 32 + lr];
#pragma unroll
        for (int r = 0; r < 16; ++r) a[r] += bias;
        acc[tt] = a;
    }
    float ss[16];
#pragma unroll
    for (int r = 0; r < 16; ++r)
        ss[r] = acc[0][r] * acc[0][r] + acc[1][r] * acc[1][r]
              + acc[2][r] * acc[2][r] + acc[3][r] * acc[3][r];
#pragma unroll
    for (int r = 0; r < 16; ++r) {
        ss[r] += __shfl_xor(ss[r], 1);  ss[r] += __shfl_xor(ss[r], 2);
        ss[r] += __shfl_xor(ss[r], 4);  ss[r] += __shfl_xor(ss[r], 8);
        ss[r] += __shfl_xor(ss[r], 16);
    }
    long nbase = (long)blockIdx.y * NR + rbase;
#pragma unroll
    for (int r = 0; r < 16; ++r) {
        float inv = 1.0f / fmaxf(sqrtf(ss[r]), 1e-12f);
        long row = nbase + (r & 3) + 8 * (r >> 2) + 4 * lh;
#pragma unroll
        for (int tt = 0; tt < 4; ++tt) {
            float v = acc[tt][r] * inv;
            gN[row * DIM + tt * 32 + lr]  = f2b(v);
            gNs[row * DIM + tt * 32 + lr] = f2b(v * SCALE_EXP2);
        }
    }
}

// ---------- fused exp-sim row sums: gT[q] += sum_j exp2(a_q . b_j) ----------
// Round-7 geometry (best measured): 512 blocks = 64 q-panels x 8 slices of 2048
// keys, block = 8 waves x 32 q-rows, NT=32. NEW: K=128 reduction split into two
// INDEPENDENT 4-deep MFMA chains (ca: kc 0-3, cb: kc 4-7) merged by 16 adds at
// the exp step — MFMA pipe sees 2-4 independent chains/wave instead of one
// 8-deep latency chain (MfmaUtil 40% == ~35cyc/MFMA == latency-bound, R12).
// launch_bounds (512,2): (512,4) empirically forces a 64-VGPR budget (R9 spill).
__global__ __launch_bounds__(512, 2) void k_sim() {
    __shared__ char smem[2 * 16384];                 // 2 x (64 keys x 256 B)
    int slice = blockIdx.x & 7, qp = blockIdx.x >> 3;
    int t = threadIdx.x, w = t >> 6, l = t & 63;
    int lr = l & 31, lh = l >> 5;
    long qbase = (long)qp * 256 + w * 32;
    long kb = (long)slice * 2048;

    short8 qf[8];
#pragma unroll
    for (int kc = 0; kc < 8; ++kc)
        qf[kc] = *(const short8*)(gNs + (qbase + lr) * DIM + kc * 16 + lh * 8);
    float rs[16];
#pragma unroll
    for (int r = 0; r < 16; ++r) rs[r] = 0.0f;

    // stage 64x128 bf16 tile (16 KB): linear LDS dest, inverse-swizzled global src
    // j = (i&~15) | ((i&15) ^ ((i>>4)&7)); read applies the same involution.
#define STAGE(BUF, TILE) do {                                                        \
    const unsigned short* _tb = gN + (kb + (long)(TILE) * 64) * DIM;                 \
    int _j0 = (t & ~15) | ((t & 15) ^ ((t >> 4) & 7));                               \
    gload_lds16(_tb + _j0 * 8, smem + (BUF) * 16384 + w * 1024);                     \
    int _i1 = 512 + t;                                                               \
    int _j1 = (_i1 & ~15) | ((_i1 & 15) ^ ((_i1 >> 4) & 7));                         \
    gload_lds16(_tb + _j1 * 8, smem + (BUF) * 16384 + 8192 + w * 1024);              \
} while (0)

    STAGE(0, 0);
    for (int tt = 0; tt < NT; ++tt) {
        int cur = tt & 1;
        if (tt + 1 < NT) {
            STAGE(cur ^ 1, tt + 1);
            asm volatile("s_waitcnt vmcnt(2)" ::: "memory");   // tile tt arrived
        } else {
            asm volatile("s_waitcnt vmcnt(0)" ::: "memory");
        }
        __builtin_amdgcn_s_barrier();
        const char* bufp = smem + cur * 16384;
#pragma unroll
        for (int ks = 0; ks < 2; ++ks) {
            short8 bf[8];
#pragma unroll
            for (int kc = 0; kc < 8; ++kc) {
                int chunk = ((kc << 1) | lh) ^ (lr & 7);
                bf[kc] = *(const short8*)(bufp + (ks * 32 + lr) * 256 + chunk * 16);
            }
            f32x16 ca = zero16(), cb = zero16();   // 2 independent 4-deep chains
#pragma unroll
            for (int kc = 0; kc < 4; ++kc) {
                ca = __builtin_amdgcn_mfma_f32_32x32x16_bf16(qf[kc],     bf[kc],     ca, 0, 0, 0);
                cb = __builtin_amdgcn_mfma_f32_32x32x16_bf16(qf[kc + 4], bf[kc + 4], cb, 0, 0, 0);
            }
#pragma unroll
            for (int r = 0; r < 16; ++r)
                rs[r] += __builtin_amdgcn_exp2f(ca[r] + cb[r]);
        }
        __builtin_amdgcn_s_barrier();   // all waves done reading before overwrite
    }
#undef STAGE

#pragma unroll
    for (int r = 0; r < 16; ++r) {
        rs[r] += __shfl_xor(rs[r], 1);  rs[r] += __shfl_xor(rs[r], 2);
        rs[r] += __shfl_xor(rs[r], 4);  rs[r] += __shfl_xor(rs[r], 8);
        rs[r] += __shfl_xor(rs[r], 16);
    }
    if (lr == 0) {   // lanes 0 / 32 own 16 rows each
#pragma unroll
        for (int r = 0; r < 16; ++r) {
            int ro = (r & 3) + 8 * (r >> 2) + 4 * lh;
            atomicAdd(&gT[qbase + ro], rs[r]);
        }
    }
}

// ---------- per-row loss + global mean (writes d_out directly) ----------
__global__ __launch_bounds__(256) void k_loss(float* __restrict__ out) {
    int t = threadIdx.x, w = t >> 6, l = t & 63;
    int gw = blockIdx.x * 4 + w;   // 512 waves
    float lsum = 0.0f;
    for (int row = gw; row < NR; row += 512) {
        unsigned int pa = *(const unsigned int*)(gN + (long)row * DIM + l * 2);
        unsigned int pb = *(const unsigned int*)(gN + (long)(NR + row) * DIM + l * 2);
        float a0 = b2f((unsigned short)(pa & 0xFFFFu)), a1 = b2f((unsigned short)(pa >> 16));
        float b0 = b2f((unsigned short)(pb & 0xFFFFu)), b1 = b2f((unsigned short)(pb >> 16));
        float sd1 = a0 * a0 + a1 * a1;
        float sd2 = b0 * b0 + b1 * b1;
        float cr  = a0 * b0 + a1 * b1;
#pragma unroll
        for (int off = 1; off < 64; off <<= 1) {
            sd1 += __shfl_xor(sd1, off);
            sd2 += __shfl_xor(sd2, off);
            cr  += __shfl_xor(cr,  off);
        }
        float d1 = gT[row]      - __builtin_amdgcn_exp2f(sd1 * SCALE_EXP2);
        float d2 = gT[NR + row] - __builtin_amdgcn_exp2f(sd2 * SCALE_EXP2);
        float v = (__builtin_amdgcn_logf(d1) + __builtin_amdgcn_logf(d2)) * LN2 - 4.0f * cr;
        if (l == 0) lsum += v;
    }
    if (l == 0) atomicAdd(out, lsum * (0.5f / 8192.0f));
}

extern "C" void kernel_launch(void* const* d_in, const int* in_sizes, int n_in,
                              void* d_out, int out_size, void* d_ws, size_t ws_size,
                              hipStream_t stream) {
    const float* z1 = (const float*)d_in[0];
    const float* z2 = (const float*)d_in[1];
    const float* w1 = (const float*)d_in[2];
    const float* b1 = (const float*)d_in[3];
    const float* w2 = (const float*)d_in[4];
    const float* b2 = (const float*)d_in[5];

    k_proj<<<dim3(64, 2), 256, 0, stream>>>(z1, z2, w1, b1, w2, b2, (float*)d_out);
    k_sim<<<dim3(512), 512, 0, stream>>>();
    k_loss<<<dim3(128), 256, 0, stream>>>((float*)d_out);
}

// Round 14
// 117.741 us; speedup vs baseline: 1.1612x; 1.1492x over previous
//
#include <hip/hip_runtime.h>

// NPairDiscriminator: N=8192, D=128, tau=0.5. f32 inputs, f32 scalar output.
// loss = mean_i 0.5*(log d1_i + log d2_i - 4*(n1_i . n2_i))
//   d1_i = T[i] - e^2,  d2_i = T[NR+i] - e^2   (|n|^2 == 1 after normalize)
// T[q] = sum over ALL 16384 keys of exp((n_q . n_j)/tau), MFMA+exp2 fused.

#define NR 8192
#define DIM 128
#define SCALE_EXP2 2.885390081777927f   // 1/(tau*ln2)
#define LOG2E 1.442695040888963f
#define LN2 0.6931471805599453f
#define E2 7.38905609893065f             // exp(1/tau) = e^2, the diag term
#define NT 32                            // 64-key tiles per 2048-key slice

typedef __attribute__((ext_vector_type(8))) short short8;    // 8 bf16 (MFMA A/B frag)
typedef __attribute__((ext_vector_type(4))) float f32x4;
typedef __attribute__((ext_vector_type(16))) float f32x16;   // 32x32 MFMA C/D frag

__device__ unsigned short gN[2 * NR * DIM];   // [n1; n2] normalized bf16 (keys)
__device__ unsigned short gNs[2 * NR * DIM];  // gN * SCALE_EXP2 bf16 (queries)
__device__ float gT[2 * NR];                  // row sums

__device__ inline float b2f(unsigned short h) {
    union { unsigned int u; float f; } x; x.u = ((unsigned int)h) << 16; return x.f;
}
__device__ inline unsigned short f2b(float f) {   // RNE f32->bf16
    union { float f; unsigned int u; } x; x.f = f;
    return (unsigned short)((x.u + 0x7FFFu + ((x.u >> 16) & 1u)) >> 16);
}
__device__ inline short8 ldf8(const float* __restrict__ p) {   // 8 f32 -> bf16 frag
    f32x4 a = *(const f32x4*)p;
    f32x4 b = *(const f32x4*)(p + 4);
    short8 r;
#pragma unroll
    for (int j = 0; j < 4; ++j) r[j] = (short)f2b(a[j]);
#pragma unroll
    for (int j = 0; j < 4; ++j) r[4 + j] = (short)f2b(b[j]);
    return r;
}
__device__ inline f32x16 zero16() {
    f32x16 z;
#pragma unroll
    for (int i = 0; i < 16; ++i) z[i] = 0.0f;
    return z;
}
__device__ inline void gload_lds16(const void* g, void* l) {   // 16B async global->LDS
    __builtin_amdgcn_global_load_lds(
        (const __attribute__((address_space(1))) unsigned int*)g,
        (__attribute__((address_space(3))) unsigned int*)l, 16, 0, 0);
}

// ---------- fused projection: n = normalize(fc2(elu(fc1(z)))); zeroes gT, d_out ----------
// grid (128, 2), block 128 = 2 waves x 32 rows -> 256 blocks, all CUs busy.
__global__ __launch_bounds__(128) void k_proj(
        const float* __restrict__ Z1, const float* __restrict__ Z2,
        const float* __restrict__ W1, const float* __restrict__ B1,
        const float* __restrict__ W2, const float* __restrict__ B2,
        float* __restrict__ out) {
    __shared__ unsigned short hfrag[2][8][64][8];   // [wave][kc][lane][j], 16 KB
    int t = threadIdx.x, w = t >> 6, l = t & 63;
    int lr = l & 31, lh = l >> 5;
    const float* Z = blockIdx.y ? Z2 : Z1;
    long rbase = (long)blockIdx.x * 64 + w * 32;

    int gi = ((int)blockIdx.y * 128 + (int)blockIdx.x) * 128 + t;
    if (gi < 2 * NR) gT[gi] = 0.0f;
    if (gi == 0) out[0] = 0.0f;

    short8 zf[8];
#pragma unroll
    for (int kc = 0; kc < 8; ++kc)
        zf[kc] = ldf8(Z + (rbase + lr) * DIM + kc * 16 + lh * 8);

    // layer 1 + elu, scatter to LDS in A-fragment layout (wave-private slice)
#pragma unroll
    for (int tt = 0; tt < 4; ++tt) {
        short8 wf[8];
#pragma unroll
        for (int kc = 0; kc < 8; ++kc)
            wf[kc] = ldf8(W1 + (tt * 32 + lr) * DIM + kc * 16 + lh * 8);
        f32x16 a = zero16();
#pragma unroll
        for (int kc = 0; kc < 8; ++kc)
            a = __builtin_amdgcn_mfma_f32_32x32x16_bf16(zf[kc], wf[kc], a, 0, 0, 0);
        float bias = B1[tt * 32 + lr];
        int col = tt * 32 + lr;
#pragma unroll
        for (int r = 0; r < 16; ++r) {
            float v = a[r] + bias;
            if (v <= 0.0f) v = __builtin_amdgcn_exp2f(v * LOG2E) - 1.0f;   // elu
            int ro = (r & 3) + 8 * (r >> 2) + 4 * lh;
            hfrag[w][col >> 4][ro | (((col >> 3) & 1) << 5)][col & 7] = f2b(v);
        }
    }
    __syncthreads();

    short8 af[8];
#pragma unroll
    for (int kc = 0; kc < 8; ++kc)
        af[kc] = *(const short8*)&hfrag[w][kc][l][0];

    f32x16 acc[4];
#pragma unroll
    for (int tt = 0; tt < 4; ++tt) {
        short8 wf[8];
#pragma unroll
        for (int kc = 0; kc < 8; ++kc)
            wf[kc] = ldf8(W2 + (tt * 32 + lr) * DIM + kc * 16 + lh * 8);
        f32x16 a = zero16();
#pragma unroll
        for (int kc = 0; kc < 8; ++kc)
            a = __builtin_amdgcn_mfma_f32_32x32x16_bf16(af[kc], wf[kc], a, 0, 0, 0);
        float bias = B2[tt * 32 + lr];
#pragma unroll
        for (int r = 0; r < 16; ++r) a[r] += bias;
        acc[tt] = a;
    }
    float ss[16];
#pragma unroll
    for (int r = 0; r < 16; ++r)
        ss[r] = acc[0][r] * acc[0][r] + acc[1][r] * acc[1][r]
              + acc[2][r] * acc[2][r] + acc[3][r] * acc[3][r];
#pragma unroll
    for (int r = 0; r < 16; ++r) {
        ss[r] += __shfl_xor(ss[r], 1);  ss[r] += __shfl_xor(ss[r], 2);
        ss[r] += __shfl_xor(ss[r], 4);  ss[r] += __shfl_xor(ss[r], 8);
        ss[r] += __shfl_xor(ss[r], 16);
    }
    long nbase = (long)blockIdx.y * NR + rbase;
#pragma unroll
    for (int r = 0; r < 16; ++r) {
        float inv = 1.0f / fmaxf(sqrtf(ss[r]), 1e-12f);
        long row = nbase + (r & 3) + 8 * (r >> 2) + 4 * lh;
#pragma unroll
        for (int tt = 0; tt < 4; ++tt) {
            float v = acc[tt][r] * inv;
            gN[row * DIM + tt * 32 + lr]  = f2b(v);
            gNs[row * DIM + tt * 32 + lr] = f2b(v * SCALE_EXP2);
        }
    }
}

// ---------- fused exp-sim row sums: gT[q] += sum_j exp2(a_q . b_j) ----------
// EXACT round-7 structure (best measured: 76.5 us, MfmaUtil 40%, VGPR 56):
// 512 blocks = 64 q-panels x 8 slices of 2048 keys; block = 8 waves x 32 q-rows;
// slice = bid&7 == XCD id under round-robin dispatch -> each XCD reads one
// 512 KB slice, L2-resident. launch_bounds (512,4) is safe at 56 VGPR.
__global__ __launch_bounds__(512, 4) void k_sim() {
    __shared__ char smem[2 * 16384];                 // 2 x (64 keys x 256 B)
    int slice = blockIdx.x & 7, qp = blockIdx.x >> 3;
    int t = threadIdx.x, w = t >> 6, l = t & 63;
    int lr = l & 31, lh = l >> 5;
    long qbase = (long)qp * 256 + w * 32;
    long kb = (long)slice * 2048;

    short8 qf[8];
#pragma unroll
    for (int kc = 0; kc < 8; ++kc)
        qf[kc] = *(const short8*)(gNs + (qbase + lr) * DIM + kc * 16 + lh * 8);
    float rs[16];
#pragma unroll
    for (int r = 0; r < 16; ++r) rs[r] = 0.0f;

    // stage 64x128 bf16 tile (16 KB): linear LDS dest, inverse-swizzled global src
    // j = (i&~15) | ((i&15) ^ ((i>>4)&7)); read applies the same involution.
#define STAGE(BUF, TILE) do {                                                        \
    const unsigned short* _tb = gN + (kb + (long)(TILE) * 64) * DIM;                 \
    int _i0 = (w << 6) | l;                                                          \
    int _j0 = (_i0 & ~15) | ((_i0 & 15) ^ ((_i0 >> 4) & 7));                         \
    gload_lds16(_tb + _j0 * 8, smem + (BUF) * 16384 + w * 1024);                     \
    int _i1 = 512 + ((w << 6) | l);                                                  \
    int _j1 = (_i1 & ~15) | ((_i1 & 15) ^ ((_i1 >> 4) & 7));                         \
    gload_lds16(_tb + _j1 * 8, smem + (BUF) * 16384 + 8192 + w * 1024);              \
} while (0)

    STAGE(0, 0);
    for (int tt = 0; tt < NT; ++tt) {
        int cur = tt & 1;
        if (tt + 1 < NT) {
            STAGE(cur ^ 1, tt + 1);
            asm volatile("s_waitcnt vmcnt(2)" ::: "memory");   // tile tt arrived
        } else {
            asm volatile("s_waitcnt vmcnt(0)" ::: "memory");
        }
        __builtin_amdgcn_s_barrier();
        const char* bufp = smem + cur * 16384;
#pragma unroll
        for (int ks = 0; ks < 2; ++ks) {
            short8 bf[8];
#pragma unroll
            for (int kc = 0; kc < 8; ++kc) {
                int chunk = ((kc << 1) | lh) ^ (lr & 7);
                bf[kc] = *(const short8*)(bufp + (ks * 32 + lr) * 256 + chunk * 16);
            }
            f32x16 c = zero16();
#pragma unroll
            for (int kc = 0; kc < 8; ++kc)
                c = __builtin_amdgcn_mfma_f32_32x32x16_bf16(qf[kc], bf[kc], c, 0, 0, 0);
#pragma unroll
            for (int r = 0; r < 16; ++r)
                rs[r] += __builtin_amdgcn_exp2f(c[r]);
        }
        __builtin_amdgcn_s_barrier();   // all waves done reading before overwrite
    }
#undef STAGE

#pragma unroll
    for (int r = 0; r < 16; ++r) {
        rs[r] += __shfl_xor(rs[r], 1);  rs[r] += __shfl_xor(rs[r], 2);
        rs[r] += __shfl_xor(rs[r], 4);  rs[r] += __shfl_xor(rs[r], 8);
        rs[r] += __shfl_xor(rs[r], 16);
    }
    if (lr == 0) {   // lanes 0 / 32 own 16 rows each
#pragma unroll
        for (int r = 0; r < 16; ++r) {
            int ro = (r & 3) + 8 * (r >> 2) + 4 * lh;
            atomicAdd(&gT[qbase + ro], rs[r]);
        }
    }
}

// ---------- per-row loss + global mean (diag term == e^2 analytically) ----------
// grid 256 x 256 = 1024 waves, 8 rows each. Only the cross-dot needs a reduction.
__global__ __launch_bounds__(256) void k_loss(float* __restrict__ out) {
    int t = threadIdx.x, w = t >> 6, l = t & 63;
    int gw = blockIdx.x * 4 + w;
    float lsum = 0.0f;
    for (int row = gw; row < NR; row += 1024) {
        unsigned int pa = *(const unsigned int*)(gN + (long)row * DIM + l * 2);
        unsigned int pb = *(const unsigned int*)(gN + (long)(NR + row) * DIM + l * 2);
        float a0 = b2f((unsigned short)(pa & 0xFFFFu)), a1 = b2f((unsigned short)(pa >> 16));
        float b0 = b2f((unsigned short)(pb & 0xFFFFu)), b1 = b2f((unsigned short)(pb >> 16));
        float cr = a0 * b0 + a1 * b1;
#pragma unroll
        for (int off = 1; off < 64; off <<= 1)
            cr += __shfl_xor(cr, off);
        if (l == 0) {
            float d1 = gT[row]      - E2;
            float d2 = gT[NR + row] - E2;
            lsum += (__builtin_amdgcn_logf(d1) + __builtin_amdgcn_logf(d2)) * LN2 - 4.0f * cr;
        }
    }
    if (l == 0) atomicAdd(out, lsum * (0.5f / 8192.0f));
}

extern "C" void kernel_launch(void* const* d_in, const int* in_sizes, int n_in,
                              void* d_out, int out_size, void* d_ws, size_t ws_size,
                              hipStream_t stream) {
    const float* z1 = (const float*)d_in[0];
    const float* z2 = (const float*)d_in[1];
    const float* w1 = (const float*)d_in[2];
    const float* b1 = (const float*)d_in[3];
    const float* w2 = (const float*)d_in[4];
    const float* b2 = (const float*)d_in[5];

    k_proj<<<dim3(128, 2), 128, 0, stream>>>(z1, z2, w1, b1, w2, b2, (float*)d_out);
    k_sim<<<dim3(512), 512, 0, stream>>>();
    k_loss<<<dim3(256), 256, 0, stream>>>((float*)d_out);
}